// Round 1
// baseline (479.374 us; speedup 1.0000x reference)
//
#include <hip/hip_runtime.h>

// Problem constants (match reference)
#define H_    64
#define W_    1024
#define B_    2
#define NPT   (H_ * W_)        // 65536 points per batch
#define NTOT  (B_ * NPT)       // 131072 total points
#define C1_   64
#define C2_   128
#define CIN_  192              // C1 + C2
#define CM_   128              // MLP width
#define NS_   3
#define DIST2_ 10000.0f        // DIST^2
#define BN_EPS_ 1e-5f
#define PTS   32               // points per block in fused kernels

// ---------------------------------------------------------------------------
// K0: structured-grid KNN. Per point: scan 5x5 window row-major (dh outer,
// dw inner), take first NS in-bounds neighbors with sq < DIST^2. Produce
// neighbor flat indices (within batch) and final interpolation weights,
// folding the reference's masking semantics:
//   d_j = found ? sqdist_j : ||xyz1||^2  (clamped at 1e-10)
//   w_j = found ? (1/d_j) / sum_k(1/d_k) : 0
// ---------------------------------------------------------------------------
__global__ __launch_bounds__(256) void knn_kernel(
    const float* __restrict__ xyz1, const float* __restrict__ xyz2,
    int* __restrict__ sel, float* __restrict__ wgt)
{
    int pt = blockIdx.x * blockDim.x + threadIdx.x;
    if (pt >= NTOT) return;
    int b = pt / NPT, n = pt % NPT;
    int h = n / W_, w = n % W_;

    const float* p1 = xyz1 + (size_t)pt * 3;
    float x1 = p1[0], y1 = p1[1], z1 = p1[2];

    const float* x2b = xyz2 + (size_t)b * NPT * 3;

    int   s0 = 0, s1 = 0, s2 = 0;
    float d0 = 0.f, d1 = 0.f, d2 = 0.f;
    int cnt = 0;

    for (int dh = -2; dh <= 2; dh++) {
        int nh = h + dh;
        bool okh = (nh >= 0) && (nh < H_);
        for (int dw = -2; dw <= 2; dw++) {
            int nw = w + dw;
            bool ok = okh && (nw >= 0) && (nw < W_);
            if (!ok) continue;
            int nidx = nh * W_ + nw;
            const float* p2 = x2b + (size_t)nidx * 3;
            float dx = p2[0] - x1, dy = p2[1] - y1, dz = p2[2] - z1;
            float sq = dx * dx + dy * dy + dz * dz;
            if (sq < DIST2_ && cnt < NS_) {
                if (cnt == 0)      { s0 = nidx; d0 = sq; }
                else if (cnt == 1) { s1 = nidx; d1 = sq; }
                else               { s2 = nidx; d2 = sq; }
                cnt++;
            }
        }
    }

    float self2 = x1 * x1 + y1 * y1 + z1 * z1;
    float dd0 = (cnt > 0) ? d0 : self2;
    float dd1 = (cnt > 1) ? d1 : self2;
    float dd2 = (cnt > 2) ? d2 : self2;
    if (dd0 < 1e-10f) dd0 = 1e-10f;
    if (dd1 < 1e-10f) dd1 = 1e-10f;
    if (dd2 < 1e-10f) dd2 = 1e-10f;
    float i0 = 1.0f / dd0, i1 = 1.0f / dd1, i2 = 1.0f / dd2;
    float norm = i0 + i1 + i2;

    sel[(size_t)pt * NS_ + 0] = (cnt > 0) ? s0 : 0;
    sel[(size_t)pt * NS_ + 1] = (cnt > 1) ? s1 : 0;
    sel[(size_t)pt * NS_ + 2] = (cnt > 2) ? s2 : 0;
    wgt[(size_t)pt * NS_ + 0] = (cnt > 0) ? i0 / norm : 0.f;
    wgt[(size_t)pt * NS_ + 1] = (cnt > 1) ? i1 / norm : 0.f;
    wgt[(size_t)pt * NS_ + 2] = (cnt > 2) ? i2 / norm : 0.f;
}

// ---------------------------------------------------------------------------
// K1: per block of PTS points: gather feat2 (3 nbrs, weighted) + feat1 into
// LDS x0[PTS][192]; then x0 @ w0 + b0 -> y0 (global), accumulating per-channel
// sum / sumsq for BN0 (LDS reduce then one global atomic per channel/stat).
// Matmul: 256 thr = 8 point-groups x 32 channel-quads; each thread computes
// 4 points x 4 channels (16 FMAs per k).
// ---------------------------------------------------------------------------
__global__ __launch_bounds__(256) void fused1_kernel(
    const float* __restrict__ feat1, const float* __restrict__ feat2,
    const int* __restrict__ sel, const float* __restrict__ wgt,
    const float* __restrict__ w0, const float* __restrict__ b0,
    float* __restrict__ y0, float* __restrict__ stats0)
{
    __shared__ float x0[PTS][CIN_ + 4];
    __shared__ int   selL[PTS][NS_];
    __shared__ float wgtL[PTS][NS_];
    __shared__ float ssum[CM_], ssq[CM_];

    const int t = threadIdx.x;
    const int pbase = blockIdx.x * PTS;   // PTS divides NPT -> single batch b

    if (t < PTS * NS_) {
        int p = t / NS_, j = t % NS_;
        selL[p][j] = sel[(size_t)(pbase + p) * NS_ + j];
        wgtL[p][j] = wgt[(size_t)(pbase + p) * NS_ + j];
    }
    if (t < CM_) { ssum[t] = 0.f; ssq[t] = 0.f; }
    __syncthreads();

    // feat1 -> x0[:, 0:64]   (32 pts x 16 float4 = 512 loads, 2 per thread)
    #pragma unroll
    for (int i = 0; i < 2; i++) {
        int idx = t + i * 256;
        int p = idx >> 4, c4 = (idx & 15) << 2;
        float4 f = *(const float4*)(feat1 + (size_t)(pbase + p) * C1_ + c4);
        *(float4*)&x0[p][c4] = f;
    }
    // interp -> x0[:, 64:192]  (32 pts x 32 float4 = 1024, 4 per thread)
    const int b = pbase / NPT;
    const float* f2b = feat2 + (size_t)b * NPT * C2_;
    #pragma unroll
    for (int i = 0; i < 4; i++) {
        int idx = t + i * 256;
        int p = idx >> 5, c4 = (idx & 31) << 2;
        float4 acc = make_float4(0.f, 0.f, 0.f, 0.f);
        #pragma unroll
        for (int j = 0; j < NS_; j++) {
            float wj = wgtL[p][j];
            const float4 f = *(const float4*)(f2b + (size_t)selL[p][j] * C2_ + c4);
            acc.x += wj * f.x; acc.y += wj * f.y;
            acc.z += wj * f.z; acc.w += wj * f.w;
        }
        *(float4*)&x0[p][C1_ + c4] = acc;
    }
    __syncthreads();

    // matmul: (PTS x 192) @ (192 x 128) + b0
    const int cg = (t & 31) << 2;        // channel quad
    const int p0 = (t >> 5) << 2;        // first of 4 points
    float4 bb = *(const float4*)(b0 + cg);
    float4 a0 = bb, a1 = bb, a2 = bb, a3 = bb;
    #pragma unroll 4
    for (int k = 0; k < CIN_; k++) {
        float4 wv = *(const float4*)(w0 + (size_t)k * CM_ + cg);
        float xa = x0[p0 + 0][k];
        float xb = x0[p0 + 1][k];
        float xc = x0[p0 + 2][k];
        float xd = x0[p0 + 3][k];
        a0.x += xa * wv.x; a0.y += xa * wv.y; a0.z += xa * wv.z; a0.w += xa * wv.w;
        a1.x += xb * wv.x; a1.y += xb * wv.y; a1.z += xb * wv.z; a1.w += xb * wv.w;
        a2.x += xc * wv.x; a2.y += xc * wv.y; a2.z += xc * wv.z; a2.w += xc * wv.w;
        a3.x += xd * wv.x; a3.y += xd * wv.y; a3.z += xd * wv.z; a3.w += xd * wv.w;
    }

    *(float4*)(y0 + (size_t)(pbase + p0 + 0) * CM_ + cg) = a0;
    *(float4*)(y0 + (size_t)(pbase + p0 + 1) * CM_ + cg) = a1;
    *(float4*)(y0 + (size_t)(pbase + p0 + 2) * CM_ + cg) = a2;
    *(float4*)(y0 + (size_t)(pbase + p0 + 3) * CM_ + cg) = a3;

    // BN0 stats: per-thread 4-point partials -> LDS atomics -> global atomics
    float sx = a0.x + a1.x + a2.x + a3.x;
    float sy = a0.y + a1.y + a2.y + a3.y;
    float sz = a0.z + a1.z + a2.z + a3.z;
    float sw = a0.w + a1.w + a2.w + a3.w;
    float qx = a0.x*a0.x + a1.x*a1.x + a2.x*a2.x + a3.x*a3.x;
    float qy = a0.y*a0.y + a1.y*a1.y + a2.y*a2.y + a3.y*a3.y;
    float qz = a0.z*a0.z + a1.z*a1.z + a2.z*a2.z + a3.z*a3.z;
    float qw = a0.w*a0.w + a1.w*a1.w + a2.w*a2.w + a3.w*a3.w;
    atomicAdd(&ssum[cg + 0], sx); atomicAdd(&ssum[cg + 1], sy);
    atomicAdd(&ssum[cg + 2], sz); atomicAdd(&ssum[cg + 3], sw);
    atomicAdd(&ssq[cg + 0], qx);  atomicAdd(&ssq[cg + 1], qy);
    atomicAdd(&ssq[cg + 2], qz);  atomicAdd(&ssq[cg + 3], qw);
    __syncthreads();
    if (t < CM_)            atomicAdd(&stats0[t], ssum[t]);
    else if (t < 2 * CM_)   atomicAdd(&stats0[t], ssq[t - CM_]);
}

// ---------------------------------------------------------------------------
// K2: BN0 finalize + ReLU on y0 tile -> LDS x1[PTS][128]; matmul1 -> writes
// into d_out (staging buffer for y1) + BN1 stats.
// ---------------------------------------------------------------------------
__global__ __launch_bounds__(256) void fused2_kernel(
    const float* __restrict__ y0, const float* __restrict__ stats0,
    const float* __restrict__ g0, const float* __restrict__ be0,
    const float* __restrict__ w1, const float* __restrict__ b1,
    float* __restrict__ y1, float* __restrict__ stats1)
{
    __shared__ float x1[PTS][CM_ + 4];
    __shared__ float scl[CM_], shf[CM_];
    __shared__ float ssum[CM_], ssq[CM_];

    const int t = threadIdx.x;
    const int pbase = blockIdx.x * PTS;

    if (t < CM_) {
        const float invn = 1.0f / (float)NTOT;
        float mu  = stats0[t] * invn;
        float var = stats0[CM_ + t] * invn - mu * mu;
        float sc  = g0[t] * rsqrtf(var + BN_EPS_);
        scl[t] = sc;
        shf[t] = be0[t] - mu * sc;
        ssum[t] = 0.f; ssq[t] = 0.f;
    }
    __syncthreads();

    // load y0 tile, BN0 + ReLU -> LDS
    #pragma unroll
    for (int i = 0; i < 4; i++) {
        int idx = t + i * 256;
        int p = idx >> 5, c4 = (idx & 31) << 2;
        float4 v = *(const float4*)(y0 + (size_t)(pbase + p) * CM_ + c4);
        v.x = fmaxf(v.x * scl[c4 + 0] + shf[c4 + 0], 0.f);
        v.y = fmaxf(v.y * scl[c4 + 1] + shf[c4 + 1], 0.f);
        v.z = fmaxf(v.z * scl[c4 + 2] + shf[c4 + 2], 0.f);
        v.w = fmaxf(v.w * scl[c4 + 3] + shf[c4 + 3], 0.f);
        *(float4*)&x1[p][c4] = v;
    }
    __syncthreads();

    const int cg = (t & 31) << 2;
    const int p0 = (t >> 5) << 2;
    float4 bb = *(const float4*)(b1 + cg);
    float4 a0 = bb, a1 = bb, a2 = bb, a3 = bb;
    #pragma unroll 4
    for (int k = 0; k < CM_; k++) {
        float4 wv = *(const float4*)(w1 + (size_t)k * CM_ + cg);
        float xa = x1[p0 + 0][k];
        float xb = x1[p0 + 1][k];
        float xc = x1[p0 + 2][k];
        float xd = x1[p0 + 3][k];
        a0.x += xa * wv.x; a0.y += xa * wv.y; a0.z += xa * wv.z; a0.w += xa * wv.w;
        a1.x += xb * wv.x; a1.y += xb * wv.y; a1.z += xb * wv.z; a1.w += xb * wv.w;
        a2.x += xc * wv.x; a2.y += xc * wv.y; a2.z += xc * wv.z; a2.w += xc * wv.w;
        a3.x += xd * wv.x; a3.y += xd * wv.y; a3.z += xd * wv.z; a3.w += xd * wv.w;
    }

    *(float4*)(y1 + (size_t)(pbase + p0 + 0) * CM_ + cg) = a0;
    *(float4*)(y1 + (size_t)(pbase + p0 + 1) * CM_ + cg) = a1;
    *(float4*)(y1 + (size_t)(pbase + p0 + 2) * CM_ + cg) = a2;
    *(float4*)(y1 + (size_t)(pbase + p0 + 3) * CM_ + cg) = a3;

    float sx = a0.x + a1.x + a2.x + a3.x;
    float sy = a0.y + a1.y + a2.y + a3.y;
    float sz = a0.z + a1.z + a2.z + a3.z;
    float sw = a0.w + a1.w + a2.w + a3.w;
    float qx = a0.x*a0.x + a1.x*a1.x + a2.x*a2.x + a3.x*a3.x;
    float qy = a0.y*a0.y + a1.y*a1.y + a2.y*a2.y + a3.y*a3.y;
    float qz = a0.z*a0.z + a1.z*a1.z + a2.z*a2.z + a3.z*a3.z;
    float qw = a0.w*a0.w + a1.w*a1.w + a2.w*a2.w + a3.w*a3.w;
    atomicAdd(&ssum[cg + 0], sx); atomicAdd(&ssum[cg + 1], sy);
    atomicAdd(&ssum[cg + 2], sz); atomicAdd(&ssum[cg + 3], sw);
    atomicAdd(&ssq[cg + 0], qx);  atomicAdd(&ssq[cg + 1], qy);
    atomicAdd(&ssq[cg + 2], qz);  atomicAdd(&ssq[cg + 3], qw);
    __syncthreads();
    if (t < CM_)            atomicAdd(&stats1[t], ssum[t]);
    else if (t < 2 * CM_)   atomicAdd(&stats1[t], ssq[t - CM_]);
}

// ---------------------------------------------------------------------------
// K3: in-place BN1 + ReLU on d_out (which holds y1). One float4 per thread.
// ---------------------------------------------------------------------------
__global__ __launch_bounds__(256) void bn_out_kernel(
    float* __restrict__ out, const float* __restrict__ stats1,
    const float* __restrict__ g1, const float* __restrict__ be1)
{
    int i = blockIdx.x * blockDim.x + threadIdx.x;   // float4 index
    int c4 = (i & 31) << 2;                          // 128 ch = 32 float4/row
    const float invn = 1.0f / (float)NTOT;

    float4 s = *(const float4*)(stats1 + c4);
    float4 q = *(const float4*)(stats1 + CM_ + c4);
    float4 g = *(const float4*)(g1 + c4);
    float4 be = *(const float4*)(be1 + c4);

    float mux = s.x * invn, muy = s.y * invn, muz = s.z * invn, muw = s.w * invn;
    float scx = g.x * rsqrtf(q.x * invn - mux * mux + BN_EPS_);
    float scy = g.y * rsqrtf(q.y * invn - muy * muy + BN_EPS_);
    float scz = g.z * rsqrtf(q.z * invn - muz * muz + BN_EPS_);
    float scw = g.w * rsqrtf(q.w * invn - muw * muw + BN_EPS_);

    float4 v = *(const float4*)(out + (size_t)i * 4);
    v.x = fmaxf((v.x - mux) * scx + be.x, 0.f);
    v.y = fmaxf((v.y - muy) * scy + be.y, 0.f);
    v.z = fmaxf((v.z - muz) * scz + be.z, 0.f);
    v.w = fmaxf((v.w - muw) * scw + be.w, 0.f);
    *(float4*)(out + (size_t)i * 4) = v;
}

// ---------------------------------------------------------------------------
extern "C" void kernel_launch(void* const* d_in, const int* in_sizes, int n_in,
                              void* d_out, int out_size, void* d_ws, size_t ws_size,
                              hipStream_t stream)
{
    const float* xyz1  = (const float*)d_in[0];
    const float* xyz2  = (const float*)d_in[1];
    const float* feat1 = (const float*)d_in[2];
    const float* feat2 = (const float*)d_in[3];
    const float* w0    = (const float*)d_in[4];
    const float* b0    = (const float*)d_in[5];
    const float* g0    = (const float*)d_in[6];
    const float* be0   = (const float*)d_in[7];
    const float* w1    = (const float*)d_in[8];
    const float* b1    = (const float*)d_in[9];
    const float* g1    = (const float*)d_in[10];
    const float* be1   = (const float*)d_in[11];
    float* out = (float*)d_out;

    char* ws = (char*)d_ws;
    // ws layout: stats0 (1KB) | stats1 (1KB) | sel (1.5MB) | wgt (1.5MB) | y0 (64MB)
    float* stats0 = (float*)(ws);
    float* stats1 = (float*)(ws + 1024);
    int*   sel    = (int*)(ws + 2048);
    float* wgt    = (float*)(ws + 2048 + (size_t)NTOT * NS_ * 4);
    float* y0     = (float*)(ws + 2048 + 2 * (size_t)NTOT * NS_ * 4);

    hipMemsetAsync(ws, 0, 2048, stream);   // zero BN stat accumulators

    knn_kernel<<<NTOT / 256, 256, 0, stream>>>(xyz1, xyz2, sel, wgt);
    fused1_kernel<<<NTOT / PTS, 256, 0, stream>>>(feat1, feat2, sel, wgt,
                                                  w0, b0, y0, stats0);
    fused2_kernel<<<NTOT / PTS, 256, 0, stream>>>(y0, stats0, g0, be0,
                                                  w1, b1, out, stats1);
    bn_out_kernel<<<(NTOT * CM_ / 4) / 256, 256, 0, stream>>>(out, stats1, g1, be1);
}

// Round 2
// 339.731 us; speedup vs baseline: 1.4110x; 1.4110x over previous
//
#include <hip/hip_runtime.h>

// Problem constants (match reference)
#define H_    64
#define W_    1024
#define B_    2
#define NPT   (H_ * W_)        // 65536 points per batch
#define NTOT  (B_ * NPT)       // 131072 total points
#define C1_   64
#define C2_   128
#define CIN_  192              // C1 + C2
#define CM_   128              // MLP width
#define NS_   3
#define DIST2_ 10000.0f        // DIST^2
#define BN_EPS_ 1e-5f
#define MT_   64               // points (M-tile) per block in fused kernels

typedef __attribute__((ext_vector_type(8))) short short8;   // 8 bf16 = 4 VGPRs
typedef __attribute__((ext_vector_type(4))) float floatx4;  // MFMA C/D

__device__ __forceinline__ unsigned short f2bf(float f) {
    unsigned int u = __float_as_uint(f);
    u += 0x7fffu + ((u >> 16) & 1u);      // round-nearest-even
    return (unsigned short)(u >> 16);
}

// ---------------------------------------------------------------------------
// prep: transpose + bf16-convert the two weight matrices into ws.
// w0 (192x128 f32) -> w0T (128x192 bf16, [n][k]); w1 (128x128) -> w1T.
// ---------------------------------------------------------------------------
__global__ __launch_bounds__(256) void prep_kernel(
    const float* __restrict__ w0, const float* __restrict__ w1,
    unsigned short* __restrict__ w0T, unsigned short* __restrict__ w1T)
{
    int i = blockIdx.x * 256 + threadIdx.x;
    if (i < CIN_ * CM_) {
        int n = i / CIN_, k = i % CIN_;
        w0T[i] = f2bf(w0[(size_t)k * CM_ + n]);
    } else {
        int j = i - CIN_ * CM_;
        if (j < CM_ * CM_) {
            int n = j / CM_, k = j % CM_;
            w1T[j] = f2bf(w1[(size_t)k * CM_ + n]);
        }
    }
}

// ---------------------------------------------------------------------------
// K0: structured-grid KNN (scan order = reference row-major window order).
// Emits neighbor indices + final inverse-distance weights (masked slots get
// weight 0 but their 1/||xyz1||^2 still enters the normalization sum).
// ---------------------------------------------------------------------------
__global__ __launch_bounds__(256) void knn_kernel(
    const float* __restrict__ xyz1, const float* __restrict__ xyz2,
    int* __restrict__ sel, float* __restrict__ wgt)
{
    int pt = blockIdx.x * blockDim.x + threadIdx.x;
    if (pt >= NTOT) return;
    int b = pt / NPT, n = pt % NPT;
    int h = n / W_, w = n % W_;

    const float* p1 = xyz1 + (size_t)pt * 3;
    float x1 = p1[0], y1 = p1[1], z1 = p1[2];
    const float* x2b = xyz2 + (size_t)b * NPT * 3;

    int   s0 = 0, s1 = 0, s2 = 0;
    float d0 = 0.f, d1 = 0.f, d2 = 0.f;
    int cnt = 0;

    for (int dh = -2; dh <= 2; dh++) {
        int nh = h + dh;
        bool okh = (nh >= 0) && (nh < H_);
        for (int dw = -2; dw <= 2; dw++) {
            int nw = w + dw;
            if (!(okh && nw >= 0 && nw < W_)) continue;
            int nidx = nh * W_ + nw;
            const float* p2 = x2b + (size_t)nidx * 3;
            float dx = p2[0] - x1, dy = p2[1] - y1, dz = p2[2] - z1;
            float sq = dx * dx + dy * dy + dz * dz;
            if (sq < DIST2_ && cnt < NS_) {
                if (cnt == 0)      { s0 = nidx; d0 = sq; }
                else if (cnt == 1) { s1 = nidx; d1 = sq; }
                else               { s2 = nidx; d2 = sq; }
                cnt++;
            }
        }
    }

    float self2 = x1 * x1 + y1 * y1 + z1 * z1;
    float dd0 = (cnt > 0) ? d0 : self2;
    float dd1 = (cnt > 1) ? d1 : self2;
    float dd2 = (cnt > 2) ? d2 : self2;
    if (dd0 < 1e-10f) dd0 = 1e-10f;
    if (dd1 < 1e-10f) dd1 = 1e-10f;
    if (dd2 < 1e-10f) dd2 = 1e-10f;
    float i0 = 1.0f / dd0, i1 = 1.0f / dd1, i2 = 1.0f / dd2;
    float norm = i0 + i1 + i2;

    sel[(size_t)pt * NS_ + 0] = (cnt > 0) ? s0 : 0;
    sel[(size_t)pt * NS_ + 1] = (cnt > 1) ? s1 : 0;
    sel[(size_t)pt * NS_ + 2] = (cnt > 2) ? s2 : 0;
    wgt[(size_t)pt * NS_ + 0] = (cnt > 0) ? i0 / norm : 0.f;
    wgt[(size_t)pt * NS_ + 1] = (cnt > 1) ? i1 / norm : 0.f;
    wgt[(size_t)pt * NS_ + 2] = (cnt > 2) ? i2 / norm : 0.f;
}

// ---------------------------------------------------------------------------
// K1: gather feat1 + IDW-interp feat2 -> bf16 LDS tile x0[64][192+8];
// MFMA matmul0 (16x16x32 bf16, K=192) with w0T streamed from global (L1-hot);
// epilogue: +b0, store y0 (f32), BN0 sum/sumsq via shuffle+LDS+global atomics.
// 4 waves/block, each wave = 16 rows x 128 cols (8 n-tiles, 32 acc VGPRs).
// ---------------------------------------------------------------------------
__global__ __launch_bounds__(256) void fused1_kernel(
    const float* __restrict__ feat1, const float* __restrict__ feat2,
    const int* __restrict__ sel, const float* __restrict__ wgt,
    const unsigned short* __restrict__ w0T, const float* __restrict__ b0,
    float* __restrict__ y0, float* __restrict__ stats0)
{
    __shared__ unsigned short x0bf[MT_][CIN_ + 8];  // +8 pad: row=400B, 16B-aligned
    __shared__ int   selL[MT_][NS_];
    __shared__ float wgtL[MT_][NS_];
    __shared__ float ssum[CM_], ssq[CM_];

    const int t = threadIdx.x;
    const int pbase = blockIdx.x * MT_;   // MT_ divides NPT -> single batch

    if (t < MT_ * NS_) {                  // contiguous (p,j) = t
        selL[t / NS_][t % NS_] = sel[(size_t)pbase * NS_ + t];
        wgtL[t / NS_][t % NS_] = wgt[(size_t)pbase * NS_ + t];
    }
    if (t < CM_) { ssum[t] = 0.f; ssq[t] = 0.f; }
    __syncthreads();

    // feat1 -> x0[:, 0:64]  (64 pts x 16 float4 = 1024 tasks)
    #pragma unroll
    for (int i = 0; i < 4; i++) {
        int idx = t + i * 256;
        int p = idx >> 4, c4 = (idx & 15) << 2;
        float4 f = *(const float4*)(feat1 + (size_t)(pbase + p) * C1_ + c4);
        ushort4 u;
        u.x = f2bf(f.x); u.y = f2bf(f.y); u.z = f2bf(f.z); u.w = f2bf(f.w);
        *(ushort4*)&x0bf[p][c4] = u;
    }
    // interp -> x0[:, 64:192]  (64 pts x 32 float4 = 2048 tasks)
    const int b = pbase / NPT;
    const float* f2b = feat2 + (size_t)b * NPT * C2_;
    #pragma unroll
    for (int i = 0; i < 8; i++) {
        int idx = t + i * 256;
        int p = idx >> 5, c4 = (idx & 31) << 2;
        float ax = 0.f, ay = 0.f, az = 0.f, aw = 0.f;
        #pragma unroll
        for (int j = 0; j < NS_; j++) {
            float wj = wgtL[p][j];
            float4 f = *(const float4*)(f2b + (size_t)selL[p][j] * C2_ + c4);
            ax += wj * f.x; ay += wj * f.y; az += wj * f.z; aw += wj * f.w;
        }
        ushort4 u;
        u.x = f2bf(ax); u.y = f2bf(ay); u.z = f2bf(az); u.w = f2bf(aw);
        *(ushort4*)&x0bf[p][C1_ + c4] = u;
    }
    __syncthreads();

    // MFMA: wave wv owns rows [wv*16, wv*16+16)
    const int wv = t >> 6, lane = t & 63;
    const int m = lane & 15, q = lane >> 4;
    const unsigned short* arow  = &x0bf[wv * 16 + m][q * 8];
    const unsigned short* bbase = w0T + (size_t)m * CIN_ + q * 8;

    floatx4 acc[8];
    #pragma unroll
    for (int nt = 0; nt < 8; nt++) acc[nt] = (floatx4){0.f, 0.f, 0.f, 0.f};

    #pragma unroll
    for (int kk = 0; kk < 6; kk++) {
        short8 a = *(const short8*)(arow + kk * 32);
        #pragma unroll
        for (int nt = 0; nt < 8; nt++) {
            short8 bw = *(const short8*)(bbase + (size_t)nt * 16 * CIN_ + kk * 32);
            acc[nt] = __builtin_amdgcn_mfma_f32_16x16x32_bf16(a, bw, acc[nt], 0, 0, 0);
        }
    }

    // epilogue: D(row = q*4+r, col = nt*16+m)
    #pragma unroll
    for (int nt = 0; nt < 8; nt++) {
        int n = nt * 16 + m;
        float bv = b0[n];
        float s = 0.f, sq2 = 0.f;
        #pragma unroll
        for (int r = 0; r < 4; r++) {
            float v = acc[nt][r] + bv;
            int row = pbase + wv * 16 + q * 4 + r;
            y0[(size_t)row * CM_ + n] = v;
            s += v; sq2 += v * v;
        }
        s += __shfl_xor(s, 16, 64); sq2 += __shfl_xor(sq2, 16, 64);
        s += __shfl_xor(s, 32, 64); sq2 += __shfl_xor(sq2, 32, 64);
        if (q == 0) { atomicAdd(&ssum[n], s); atomicAdd(&ssq[n], sq2); }
    }
    __syncthreads();
    if (t < CM_)          atomicAdd(&stats0[t], ssum[t]);
    else if (t < 2 * CM_) atomicAdd(&stats0[t], ssq[t - CM_]);
}

// ---------------------------------------------------------------------------
// K2: BN0+ReLU on y0 tile -> bf16 LDS x1[64][128+8]; MFMA matmul1 (K=128);
// epilogue: +b1, store y1 into d_out + BN1 stats.
// ---------------------------------------------------------------------------
__global__ __launch_bounds__(256) void fused2_kernel(
    const float* __restrict__ y0, const float* __restrict__ stats0,
    const float* __restrict__ g0, const float* __restrict__ be0,
    const unsigned short* __restrict__ w1T, const float* __restrict__ b1,
    float* __restrict__ y1, float* __restrict__ stats1)
{
    __shared__ unsigned short x1bf[MT_][CM_ + 8];   // row = 272B, 16B-aligned
    __shared__ float scl[CM_], shf[CM_];
    __shared__ float ssum[CM_], ssq[CM_];

    const int t = threadIdx.x;
    const int pbase = blockIdx.x * MT_;

    if (t < CM_) {
        const float invn = 1.0f / (float)NTOT;
        float mu  = stats0[t] * invn;
        float var = stats0[CM_ + t] * invn - mu * mu;
        float sc  = g0[t] * rsqrtf(var + BN_EPS_);
        scl[t] = sc;
        shf[t] = be0[t] - mu * sc;
        ssum[t] = 0.f; ssq[t] = 0.f;
    }
    __syncthreads();

    #pragma unroll
    for (int i = 0; i < 8; i++) {
        int idx = t + i * 256;                 // 64 pts x 32 float4
        int p = idx >> 5, c4 = (idx & 31) << 2;
        float4 v = *(const float4*)(y0 + (size_t)(pbase + p) * CM_ + c4);
        v.x = fmaxf(v.x * scl[c4 + 0] + shf[c4 + 0], 0.f);
        v.y = fmaxf(v.y * scl[c4 + 1] + shf[c4 + 1], 0.f);
        v.z = fmaxf(v.z * scl[c4 + 2] + shf[c4 + 2], 0.f);
        v.w = fmaxf(v.w * scl[c4 + 3] + shf[c4 + 3], 0.f);
        ushort4 u;
        u.x = f2bf(v.x); u.y = f2bf(v.y); u.z = f2bf(v.z); u.w = f2bf(v.w);
        *(ushort4*)&x1bf[p][c4] = u;
    }
    __syncthreads();

    const int wv = t >> 6, lane = t & 63;
    const int m = lane & 15, q = lane >> 4;
    const unsigned short* arow  = &x1bf[wv * 16 + m][q * 8];
    const unsigned short* bbase = w1T + (size_t)m * CM_ + q * 8;

    floatx4 acc[8];
    #pragma unroll
    for (int nt = 0; nt < 8; nt++) acc[nt] = (floatx4){0.f, 0.f, 0.f, 0.f};

    #pragma unroll
    for (int kk = 0; kk < 4; kk++) {
        short8 a = *(const short8*)(arow + kk * 32);
        #pragma unroll
        for (int nt = 0; nt < 8; nt++) {
            short8 bw = *(const short8*)(bbase + (size_t)nt * 16 * CM_ + kk * 32);
            acc[nt] = __builtin_amdgcn_mfma_f32_16x16x32_bf16(a, bw, acc[nt], 0, 0, 0);
        }
    }

    #pragma unroll
    for (int nt = 0; nt < 8; nt++) {
        int n = nt * 16 + m;
        float bv = b1[n];
        float s = 0.f, sq2 = 0.f;
        #pragma unroll
        for (int r = 0; r < 4; r++) {
            float v = acc[nt][r] + bv;
            int row = pbase + wv * 16 + q * 4 + r;
            y1[(size_t)row * CM_ + n] = v;
            s += v; sq2 += v * v;
        }
        s += __shfl_xor(s, 16, 64); sq2 += __shfl_xor(sq2, 16, 64);
        s += __shfl_xor(s, 32, 64); sq2 += __shfl_xor(sq2, 32, 64);
        if (q == 0) { atomicAdd(&ssum[n], s); atomicAdd(&ssq[n], sq2); }
    }
    __syncthreads();
    if (t < CM_)          atomicAdd(&stats1[t], ssum[t]);
    else if (t < 2 * CM_) atomicAdd(&stats1[t], ssq[t - CM_]);
}

// ---------------------------------------------------------------------------
// K3: in-place BN1 + ReLU on d_out (holds y1). One float4 per thread.
// ---------------------------------------------------------------------------
__global__ __launch_bounds__(256) void bn_out_kernel(
    float* __restrict__ out, const float* __restrict__ stats1,
    const float* __restrict__ g1, const float* __restrict__ be1)
{
    int i = blockIdx.x * blockDim.x + threadIdx.x;   // float4 index
    int c4 = (i & 31) << 2;
    const float invn = 1.0f / (float)NTOT;

    float4 s = *(const float4*)(stats1 + c4);
    float4 q = *(const float4*)(stats1 + CM_ + c4);
    float4 g = *(const float4*)(g1 + c4);
    float4 be = *(const float4*)(be1 + c4);

    float mux = s.x * invn, muy = s.y * invn, muz = s.z * invn, muw = s.w * invn;
    float scx = g.x * rsqrtf(q.x * invn - mux * mux + BN_EPS_);
    float scy = g.y * rsqrtf(q.y * invn - muy * muy + BN_EPS_);
    float scz = g.z * rsqrtf(q.z * invn - muz * muz + BN_EPS_);
    float scw = g.w * rsqrtf(q.w * invn - muw * muw + BN_EPS_);

    float4 v = *(const float4*)(out + (size_t)i * 4);
    v.x = fmaxf((v.x - mux) * scx + be.x, 0.f);
    v.y = fmaxf((v.y - muy) * scy + be.y, 0.f);
    v.z = fmaxf((v.z - muz) * scz + be.z, 0.f);
    v.w = fmaxf((v.w - muw) * scw + be.w, 0.f);
    *(float4*)(out + (size_t)i * 4) = v;
}

// ---------------------------------------------------------------------------
extern "C" void kernel_launch(void* const* d_in, const int* in_sizes, int n_in,
                              void* d_out, int out_size, void* d_ws, size_t ws_size,
                              hipStream_t stream)
{
    const float* xyz1  = (const float*)d_in[0];
    const float* xyz2  = (const float*)d_in[1];
    const float* feat1 = (const float*)d_in[2];
    const float* feat2 = (const float*)d_in[3];
    const float* w0    = (const float*)d_in[4];
    const float* b0    = (const float*)d_in[5];
    const float* g0    = (const float*)d_in[6];
    const float* be0   = (const float*)d_in[7];
    const float* w1    = (const float*)d_in[8];
    const float* b1    = (const float*)d_in[9];
    const float* g1    = (const float*)d_in[10];
    const float* be1   = (const float*)d_in[11];
    float* out = (float*)d_out;

    char* ws = (char*)d_ws;
    // ws: stats0 1KB | stats1 1KB | sel 1.5MB | wgt 1.5MB | w0T 48KB | w1T 32KB | y0 64MB
    float* stats0          = (float*)(ws);
    float* stats1          = (float*)(ws + 1024);
    int*   sel             = (int*)(ws + 2048);
    float* wgt             = (float*)(ws + 2048 + (size_t)NTOT * NS_ * 4);
    unsigned short* w0T    = (unsigned short*)(ws + 2048 + 2 * (size_t)NTOT * NS_ * 4);
    unsigned short* w1T    = (unsigned short*)((char*)w0T + (size_t)CIN_ * CM_ * 2);
    float* y0              = (float*)((char*)w1T + (size_t)CM_ * CM_ * 2);

    hipMemsetAsync(ws, 0, 2048, stream);   // zero BN stat accumulators

    prep_kernel<<<(CIN_ * CM_ + CM_ * CM_ + 255) / 256, 256, 0, stream>>>(w0, w1, w0T, w1T);
    knn_kernel<<<NTOT / 256, 256, 0, stream>>>(xyz1, xyz2, sel, wgt);
    fused1_kernel<<<NTOT / MT_, 256, 0, stream>>>(feat1, feat2, sel, wgt,
                                                  w0T, b0, y0, stats0);
    fused2_kernel<<<NTOT / MT_, 256, 0, stream>>>(y0, stats0, g0, be0,
                                                  w1T, b1, out, stats1);
    bn_out_kernel<<<(NTOT * CM_ / 4) / 256, 256, 0, stream>>>(out, stats1, g1, be1);
}

// Round 3
// 289.044 us; speedup vs baseline: 1.6585x; 1.1754x over previous
//
#include <hip/hip_runtime.h>

// Problem constants (match reference)
#define H_    64
#define W_    1024
#define B_    2
#define NPT   (H_ * W_)        // 65536 points per batch
#define NTOT  (B_ * NPT)       // 131072 total points
#define C1_   64
#define C2_   128
#define CIN_  192              // C1 + C2
#define CM_   128              // MLP width
#define NS_   3
#define DIST2_ 10000.0f        // DIST^2
#define BN_EPS_ 1e-5f
#define MT_   64               // points (M-tile) per block in fused kernels
#define NSLOT 32               // BN-stat accumulator slots (atomic fan-in / 64)

typedef __attribute__((ext_vector_type(8))) short short8;   // 8 bf16 = 4 VGPRs
typedef __attribute__((ext_vector_type(4))) float floatx4;  // MFMA C/D

__device__ __forceinline__ unsigned short f2bf(float f) {
    unsigned int u = __float_as_uint(f);
    u += 0x7fffu + ((u >> 16) & 1u);      // round-nearest-even
    return (unsigned short)(u >> 16);
}

// ---------------------------------------------------------------------------
// prep: transpose + bf16-convert weights. w0(192x128)->w0T(128x192 [n][k]);
// w1(128x128)->w1T.
// ---------------------------------------------------------------------------
__global__ __launch_bounds__(256) void prep_kernel(
    const float* __restrict__ w0, const float* __restrict__ w1,
    unsigned short* __restrict__ w0T, unsigned short* __restrict__ w1T)
{
    int i = blockIdx.x * 256 + threadIdx.x;
    if (i < CIN_ * CM_) {
        int n = i / CIN_, k = i % CIN_;
        w0T[i] = f2bf(w0[(size_t)k * CM_ + n]);
    } else {
        int j = i - CIN_ * CM_;
        if (j < CM_ * CM_) {
            int n = j / CM_, k = j % CM_;
            w1T[j] = f2bf(w1[(size_t)k * CM_ + n]);
        }
    }
}

// ---------------------------------------------------------------------------
// reduce: fold NSLOT slot-accumulators into final stats[256] (sum|sumsq).
// ---------------------------------------------------------------------------
__global__ __launch_bounds__(256) void reduce_slots_kernel(
    const float* __restrict__ slots, float* __restrict__ stats)
{
    int t = threadIdx.x;
    float s = 0.f;
    #pragma unroll
    for (int i = 0; i < NSLOT; i++) s += slots[i * 256 + t];
    stats[t] = s;
}

// ---------------------------------------------------------------------------
// K0: structured-grid KNN (reference scan order), emits indices + IDW weights.
// ---------------------------------------------------------------------------
__global__ __launch_bounds__(256) void knn_kernel(
    const float* __restrict__ xyz1, const float* __restrict__ xyz2,
    int* __restrict__ sel, float* __restrict__ wgt)
{
    int pt = blockIdx.x * blockDim.x + threadIdx.x;
    if (pt >= NTOT) return;
    int b = pt / NPT, n = pt % NPT;
    int h = n / W_, w = n % W_;

    const float* p1 = xyz1 + (size_t)pt * 3;
    float x1 = p1[0], y1 = p1[1], z1 = p1[2];
    const float* x2b = xyz2 + (size_t)b * NPT * 3;

    int   s0 = 0, s1 = 0, s2 = 0;
    float d0 = 0.f, d1 = 0.f, d2 = 0.f;
    int cnt = 0;

    for (int dh = -2; dh <= 2; dh++) {
        int nh = h + dh;
        bool okh = (nh >= 0) && (nh < H_);
        for (int dw = -2; dw <= 2; dw++) {
            int nw = w + dw;
            if (!(okh && nw >= 0 && nw < W_)) continue;
            int nidx = nh * W_ + nw;
            const float* p2 = x2b + (size_t)nidx * 3;
            float dx = p2[0] - x1, dy = p2[1] - y1, dz = p2[2] - z1;
            float sq = dx * dx + dy * dy + dz * dz;
            if (sq < DIST2_ && cnt < NS_) {
                if (cnt == 0)      { s0 = nidx; d0 = sq; }
                else if (cnt == 1) { s1 = nidx; d1 = sq; }
                else               { s2 = nidx; d2 = sq; }
                cnt++;
            }
        }
    }

    float self2 = x1 * x1 + y1 * y1 + z1 * z1;
    float dd0 = (cnt > 0) ? d0 : self2;
    float dd1 = (cnt > 1) ? d1 : self2;
    float dd2 = (cnt > 2) ? d2 : self2;
    if (dd0 < 1e-10f) dd0 = 1e-10f;
    if (dd1 < 1e-10f) dd1 = 1e-10f;
    if (dd2 < 1e-10f) dd2 = 1e-10f;
    float i0 = 1.0f / dd0, i1 = 1.0f / dd1, i2 = 1.0f / dd2;
    float norm = i0 + i1 + i2;

    sel[(size_t)pt * NS_ + 0] = (cnt > 0) ? s0 : 0;
    sel[(size_t)pt * NS_ + 1] = (cnt > 1) ? s1 : 0;
    sel[(size_t)pt * NS_ + 2] = (cnt > 2) ? s2 : 0;
    wgt[(size_t)pt * NS_ + 0] = (cnt > 0) ? i0 / norm : 0.f;
    wgt[(size_t)pt * NS_ + 1] = (cnt > 1) ? i1 / norm : 0.f;
    wgt[(size_t)pt * NS_ + 2] = (cnt > 2) ? i2 / norm : 0.f;
}

// ---------------------------------------------------------------------------
// K1: gather+interp -> bf16 LDS tile; MFMA matmul0; epilogue: +b0, store y0,
// BN0 stats via shfl -> per-wave LDS rows (no atomics) -> slotted global
// atomics (64 adds/address max).
// ---------------------------------------------------------------------------
__global__ __launch_bounds__(256) void fused1_kernel(
    const float* __restrict__ feat1, const float* __restrict__ feat2,
    const int* __restrict__ sel, const float* __restrict__ wgt,
    const unsigned short* __restrict__ w0T, const float* __restrict__ b0,
    float* __restrict__ y0, float* __restrict__ slots0)
{
    __shared__ unsigned short x0bf[MT_][CIN_ + 8];  // row=400B
    __shared__ int   selL[MT_][NS_];
    __shared__ float wgtL[MT_][NS_];
    __shared__ float wsum[4][CM_], wsq[4][CM_];

    const int t = threadIdx.x;
    const int pbase = blockIdx.x * MT_;   // MT_ divides NPT -> single batch

    if (t < MT_ * NS_) {
        selL[t / NS_][t % NS_] = sel[(size_t)pbase * NS_ + t];
        wgtL[t / NS_][t % NS_] = wgt[(size_t)pbase * NS_ + t];
    }
    __syncthreads();

    // feat1 -> x0[:, 0:64]
    #pragma unroll
    for (int i = 0; i < 4; i++) {
        int idx = t + i * 256;
        int p = idx >> 4, c4 = (idx & 15) << 2;
        float4 f = *(const float4*)(feat1 + (size_t)(pbase + p) * C1_ + c4);
        ushort4 u;
        u.x = f2bf(f.x); u.y = f2bf(f.y); u.z = f2bf(f.z); u.w = f2bf(f.w);
        *(ushort4*)&x0bf[p][c4] = u;
    }
    // interp -> x0[:, 64:192]
    const int b = pbase / NPT;
    const float* f2b = feat2 + (size_t)b * NPT * C2_;
    #pragma unroll
    for (int i = 0; i < 8; i++) {
        int idx = t + i * 256;
        int p = idx >> 5, c4 = (idx & 31) << 2;
        float ax = 0.f, ay = 0.f, az = 0.f, aw = 0.f;
        #pragma unroll
        for (int j = 0; j < NS_; j++) {
            float wj = wgtL[p][j];
            float4 f = *(const float4*)(f2b + (size_t)selL[p][j] * C2_ + c4);
            ax += wj * f.x; ay += wj * f.y; az += wj * f.z; aw += wj * f.w;
        }
        ushort4 u;
        u.x = f2bf(ax); u.y = f2bf(ay); u.z = f2bf(az); u.w = f2bf(aw);
        *(ushort4*)&x0bf[p][C1_ + c4] = u;
    }
    __syncthreads();

    // MFMA: wave wv owns rows [wv*16, wv*16+16)
    const int wv = t >> 6, lane = t & 63;
    const int m = lane & 15, q = lane >> 4;
    const unsigned short* arow  = &x0bf[wv * 16 + m][q * 8];
    const unsigned short* bbase = w0T + (size_t)m * CIN_ + q * 8;

    floatx4 acc[8];
    #pragma unroll
    for (int nt = 0; nt < 8; nt++) acc[nt] = (floatx4){0.f, 0.f, 0.f, 0.f};

    #pragma unroll
    for (int kk = 0; kk < 6; kk++) {
        short8 a = *(const short8*)(arow + kk * 32);
        #pragma unroll
        for (int nt = 0; nt < 8; nt++) {
            short8 bw = *(const short8*)(bbase + (size_t)nt * 16 * CIN_ + kk * 32);
            acc[nt] = __builtin_amdgcn_mfma_f32_16x16x32_bf16(a, bw, acc[nt], 0, 0, 0);
        }
    }

    // epilogue: D(row = q*4+r, col = nt*16+m)
    #pragma unroll
    for (int nt = 0; nt < 8; nt++) {
        int n = nt * 16 + m;
        float bv = b0[n];
        float s = 0.f, sq2 = 0.f;
        #pragma unroll
        for (int r = 0; r < 4; r++) {
            float v = acc[nt][r] + bv;
            int row = pbase + wv * 16 + q * 4 + r;
            y0[(size_t)row * CM_ + n] = v;
            s += v; sq2 += v * v;
        }
        s += __shfl_xor(s, 16, 64); sq2 += __shfl_xor(sq2, 16, 64);
        s += __shfl_xor(s, 32, 64); sq2 += __shfl_xor(sq2, 32, 64);
        if (q == 0) { wsum[wv][n] = s; wsq[wv][n] = sq2; }  // unique writer
    }
    __syncthreads();

    float* slot = slots0 + (size_t)(blockIdx.x & (NSLOT - 1)) * 256;
    if (t < CM_) {
        float s = wsum[0][t] + wsum[1][t] + wsum[2][t] + wsum[3][t];
        atomicAdd(&slot[t], s);
    } else if (t < 2 * CM_) {
        int n = t - CM_;
        float s = wsq[0][n] + wsq[1][n] + wsq[2][n] + wsq[3][n];
        atomicAdd(&slot[CM_ + n], s);
    }
}

// ---------------------------------------------------------------------------
// K2: BN0+ReLU on y0 tile -> bf16 LDS; MFMA matmul1; epilogue: +b1, store y1
// into d_out + BN1 stats (same slotted scheme).
// ---------------------------------------------------------------------------
__global__ __launch_bounds__(256) void fused2_kernel(
    const float* __restrict__ y0, const float* __restrict__ stats0,
    const float* __restrict__ g0, const float* __restrict__ be0,
    const unsigned short* __restrict__ w1T, const float* __restrict__ b1,
    float* __restrict__ y1, float* __restrict__ slots1)
{
    __shared__ unsigned short x1bf[MT_][CM_ + 8];   // row = 272B
    __shared__ float scl[CM_], shf[CM_];
    __shared__ float wsum[4][CM_], wsq[4][CM_];

    const int t = threadIdx.x;
    const int pbase = blockIdx.x * MT_;

    if (t < CM_) {
        const float invn = 1.0f / (float)NTOT;
        float mu  = stats0[t] * invn;
        float var = stats0[CM_ + t] * invn - mu * mu;
        float sc  = g0[t] * rsqrtf(var + BN_EPS_);
        scl[t] = sc;
        shf[t] = be0[t] - mu * sc;
    }
    __syncthreads();

    #pragma unroll
    for (int i = 0; i < 8; i++) {
        int idx = t + i * 256;
        int p = idx >> 5, c4 = (idx & 31) << 2;
        float4 v = *(const float4*)(y0 + (size_t)(pbase + p) * CM_ + c4);
        v.x = fmaxf(v.x * scl[c4 + 0] + shf[c4 + 0], 0.f);
        v.y = fmaxf(v.y * scl[c4 + 1] + shf[c4 + 1], 0.f);
        v.z = fmaxf(v.z * scl[c4 + 2] + shf[c4 + 2], 0.f);
        v.w = fmaxf(v.w * scl[c4 + 3] + shf[c4 + 3], 0.f);
        ushort4 u;
        u.x = f2bf(v.x); u.y = f2bf(v.y); u.z = f2bf(v.z); u.w = f2bf(v.w);
        *(ushort4*)&x1bf[p][c4] = u;
    }
    __syncthreads();

    const int wv = t >> 6, lane = t & 63;
    const int m = lane & 15, q = lane >> 4;
    const unsigned short* arow  = &x1bf[wv * 16 + m][q * 8];
    const unsigned short* bbase = w1T + (size_t)m * CM_ + q * 8;

    floatx4 acc[8];
    #pragma unroll
    for (int nt = 0; nt < 8; nt++) acc[nt] = (floatx4){0.f, 0.f, 0.f, 0.f};

    #pragma unroll
    for (int kk = 0; kk < 4; kk++) {
        short8 a = *(const short8*)(arow + kk * 32);
        #pragma unroll
        for (int nt = 0; nt < 8; nt++) {
            short8 bw = *(const short8*)(bbase + (size_t)nt * 16 * CM_ + kk * 32);
            acc[nt] = __builtin_amdgcn_mfma_f32_16x16x32_bf16(a, bw, acc[nt], 0, 0, 0);
        }
    }

    #pragma unroll
    for (int nt = 0; nt < 8; nt++) {
        int n = nt * 16 + m;
        float bv = b1[n];
        float s = 0.f, sq2 = 0.f;
        #pragma unroll
        for (int r = 0; r < 4; r++) {
            float v = acc[nt][r] + bv;
            int row = pbase + wv * 16 + q * 4 + r;
            y1[(size_t)row * CM_ + n] = v;
            s += v; sq2 += v * v;
        }
        s += __shfl_xor(s, 16, 64); sq2 += __shfl_xor(sq2, 16, 64);
        s += __shfl_xor(s, 32, 64); sq2 += __shfl_xor(sq2, 32, 64);
        if (q == 0) { wsum[wv][n] = s; wsq[wv][n] = sq2; }
    }
    __syncthreads();

    float* slot = slots1 + (size_t)(blockIdx.x & (NSLOT - 1)) * 256;
    if (t < CM_) {
        float s = wsum[0][t] + wsum[1][t] + wsum[2][t] + wsum[3][t];
        atomicAdd(&slot[t], s);
    } else if (t < 2 * CM_) {
        int n = t - CM_;
        float s = wsq[0][n] + wsq[1][n] + wsq[2][n] + wsq[3][n];
        atomicAdd(&slot[CM_ + n], s);
    }
}

// ---------------------------------------------------------------------------
// K3: in-place BN1 + ReLU on d_out (holds y1).
// ---------------------------------------------------------------------------
__global__ __launch_bounds__(256) void bn_out_kernel(
    float* __restrict__ out, const float* __restrict__ stats1,
    const float* __restrict__ g1, const float* __restrict__ be1)
{
    int i = blockIdx.x * blockDim.x + threadIdx.x;   // float4 index
    int c4 = (i & 31) << 2;
    const float invn = 1.0f / (float)NTOT;

    float4 s = *(const float4*)(stats1 + c4);
    float4 q = *(const float4*)(stats1 + CM_ + c4);
    float4 g = *(const float4*)(g1 + c4);
    float4 be = *(const float4*)(be1 + c4);

    float mux = s.x * invn, muy = s.y * invn, muz = s.z * invn, muw = s.w * invn;
    float scx = g.x * rsqrtf(q.x * invn - mux * mux + BN_EPS_);
    float scy = g.y * rsqrtf(q.y * invn - muy * muy + BN_EPS_);
    float scz = g.z * rsqrtf(q.z * invn - muz * muz + BN_EPS_);
    float scw = g.w * rsqrtf(q.w * invn - muw * muw + BN_EPS_);

    float4 v = *(const float4*)(out + (size_t)i * 4);
    v.x = fmaxf((v.x - mux) * scx + be.x, 0.f);
    v.y = fmaxf((v.y - muy) * scy + be.y, 0.f);
    v.z = fmaxf((v.z - muz) * scz + be.z, 0.f);
    v.w = fmaxf((v.w - muw) * scw + be.w, 0.f);
    *(float4*)(out + (size_t)i * 4) = v;
}

// ---------------------------------------------------------------------------
extern "C" void kernel_launch(void* const* d_in, const int* in_sizes, int n_in,
                              void* d_out, int out_size, void* d_ws, size_t ws_size,
                              hipStream_t stream)
{
    const float* xyz1  = (const float*)d_in[0];
    const float* xyz2  = (const float*)d_in[1];
    const float* feat1 = (const float*)d_in[2];
    const float* feat2 = (const float*)d_in[3];
    const float* w0    = (const float*)d_in[4];
    const float* b0    = (const float*)d_in[5];
    const float* g0    = (const float*)d_in[6];
    const float* be0   = (const float*)d_in[7];
    const float* w1    = (const float*)d_in[8];
    const float* b1    = (const float*)d_in[9];
    const float* g1    = (const float*)d_in[10];
    const float* be1   = (const float*)d_in[11];
    float* out = (float*)d_out;

    char* ws = (char*)d_ws;
    // ws: stats0 1K | stats1 1K | slots0 32K | slots1 32K | sel 1.5M | wgt 1.5M
    //     | w0T 48K | w1T 32K | y0 64M
    float* stats0       = (float*)(ws);
    float* stats1       = (float*)(ws + 1024);
    float* slots0       = (float*)(ws + 2048);
    float* slots1       = (float*)(ws + 2048 + NSLOT * 256 * 4);
    char*  p            = ws + 2048 + 2 * NSLOT * 256 * 4;
    int*   sel          = (int*)p;                       p += (size_t)NTOT * NS_ * 4;
    float* wgt          = (float*)p;                     p += (size_t)NTOT * NS_ * 4;
    unsigned short* w0T = (unsigned short*)p;            p += (size_t)CIN_ * CM_ * 2;
    unsigned short* w1T = (unsigned short*)p;            p += (size_t)CM_ * CM_ * 2;
    float* y0           = (float*)p;

    hipMemsetAsync(ws, 0, 2048 + 2 * NSLOT * 256 * 4, stream);  // zero stats+slots

    prep_kernel<<<(CIN_ * CM_ + CM_ * CM_ + 255) / 256, 256, 0, stream>>>(w0, w1, w0T, w1T);
    knn_kernel<<<NTOT / 256, 256, 0, stream>>>(xyz1, xyz2, sel, wgt);
    fused1_kernel<<<NTOT / MT_, 256, 0, stream>>>(feat1, feat2, sel, wgt,
                                                  w0T, b0, y0, slots0);
    reduce_slots_kernel<<<1, 256, 0, stream>>>(slots0, stats0);
    fused2_kernel<<<NTOT / MT_, 256, 0, stream>>>(y0, stats0, g0, be0,
                                                  w1T, b1, out, slots1);
    reduce_slots_kernel<<<1, 256, 0, stream>>>(slots1, stats1);
    bn_out_kernel<<<(NTOT * CM_ / 4) / 256, 256, 0, stream>>>(out, stats1, g1, be1);
}

// Round 5
// 227.560 us; speedup vs baseline: 2.1066x; 1.2702x over previous
//
#include <hip/hip_runtime.h>

// Problem constants (match reference)
#define H_    64
#define W_    1024
#define NPT   65536            // H*W
#define NTOT  131072           // B*NPT
#define C1_   64
#define C2_   128
#define CIN_  192
#define CM_   128
#define NS_   3
#define DIST2_ 10000.0f
#define BN_EPS_ 1e-5f
#define NSLOT 32               // BN-stat accumulator slots

typedef __attribute__((ext_vector_type(8))) short short8;   // 8 bf16
typedef __attribute__((ext_vector_type(4))) float floatx4;  // MFMA C/D

static __device__ __forceinline__ unsigned short f2bf(float f) {
    unsigned int u = __float_as_uint(f);
    u += 0x7fffu + ((u >> 16) & 1u);      // round-nearest-even
    return (unsigned short)(u >> 16);
}
static __device__ __forceinline__ float bflo(unsigned u) { return __uint_as_float(u << 16); }
static __device__ __forceinline__ float bfhi(unsigned u) { return __uint_as_float(u & 0xffff0000u); }
static __device__ __forceinline__ unsigned packbf(float a, float b) {
    return (unsigned)f2bf(a) | ((unsigned)f2bf(b) << 16);
}

// ---------------------------------------------------------------------------
// K0: blocks 0..19 build fragment-major bf16 weights:
//   w0F[((kk*8+nt)*64 + lane)*8 + j] = bf16(w0[(kk*32 + (lane>>4)*8 + j)][nt*16 + (lane&15)])
// so each MFMA B-frag load is one coalesced sequential 1KB wave-fetch.
// Blocks 20.. do structured-grid KNN (reference 5x5 row-major scan order).
// ---------------------------------------------------------------------------
__global__ __launch_bounds__(256) void prep_knn_kernel(
    const float* __restrict__ w0, const float* __restrict__ w1,
    const float* __restrict__ xyz1, const float* __restrict__ xyz2,
    unsigned short* __restrict__ w0F, unsigned short* __restrict__ w1F,
    int* __restrict__ sel, float* __restrict__ wgt)
{
    const int blk = blockIdx.x;
    if (blk < 20) {
        int tid = blk * 256 + threadIdx.x;
        if (tid < 3072) {                       // w0F: 6kk x 8nt x 64lane chunks
            int c = tid, lane = c & 63, nt = (c >> 6) & 7, kk = c >> 9;
            int n = nt * 16 + (lane & 15);
            int kb = kk * 32 + (lane >> 4) * 8;
            #pragma unroll
            for (int j = 0; j < 8; j++)
                w0F[(size_t)c * 8 + j] = f2bf(w0[(size_t)(kb + j) * CM_ + n]);
        } else if (tid < 5120) {                // w1F: 4kk x 8nt x 64lane
            int c = tid - 3072, lane = c & 63, nt = (c >> 6) & 7, kk = c >> 9;
            int n = nt * 16 + (lane & 15);
            int kb = kk * 32 + (lane >> 4) * 8;
            #pragma unroll
            for (int j = 0; j < 8; j++)
                w1F[(size_t)c * 8 + j] = f2bf(w1[(size_t)(kb + j) * CM_ + n]);
        }
        return;
    }

    int pt = (blk - 20) * 256 + threadIdx.x;
    if (pt >= NTOT) return;
    int bidx = pt / NPT, n = pt % NPT;
    int h = n / W_, w = n % W_;

    const float* p1 = xyz1 + (size_t)pt * 3;
    float x1 = p1[0], y1 = p1[1], z1 = p1[2];
    const float* x2b = xyz2 + (size_t)bidx * NPT * 3;

    int   s0 = 0, s1 = 0, s2 = 0;
    float d0 = 0.f, d1 = 0.f, d2 = 0.f;
    int cnt = 0;
    for (int dh = -2; dh <= 2; dh++) {
        int nh = h + dh;
        bool okh = (nh >= 0) && (nh < H_);
        for (int dw = -2; dw <= 2; dw++) {
            int nw = w + dw;
            if (!(okh && nw >= 0 && nw < W_)) continue;
            int nidx = nh * W_ + nw;
            const float* p2 = x2b + (size_t)nidx * 3;
            float dx = p2[0] - x1, dy = p2[1] - y1, dz = p2[2] - z1;
            float sq = dx * dx + dy * dy + dz * dz;
            if (sq < DIST2_ && cnt < NS_) {
                if (cnt == 0)      { s0 = nidx; d0 = sq; }
                else if (cnt == 1) { s1 = nidx; d1 = sq; }
                else               { s2 = nidx; d2 = sq; }
                cnt++;
            }
        }
    }
    float self2 = x1 * x1 + y1 * y1 + z1 * z1;
    float dd0 = (cnt > 0) ? d0 : self2;
    float dd1 = (cnt > 1) ? d1 : self2;
    float dd2 = (cnt > 2) ? d2 : self2;
    dd0 = fmaxf(dd0, 1e-10f); dd1 = fmaxf(dd1, 1e-10f); dd2 = fmaxf(dd2, 1e-10f);
    float i0 = 1.0f / dd0, i1 = 1.0f / dd1, i2 = 1.0f / dd2;
    float norm = i0 + i1 + i2;
    sel[(size_t)pt * NS_ + 0] = (cnt > 0) ? s0 : 0;
    sel[(size_t)pt * NS_ + 1] = (cnt > 1) ? s1 : 0;
    sel[(size_t)pt * NS_ + 2] = (cnt > 2) ? s2 : 0;
    wgt[(size_t)pt * NS_ + 0] = (cnt > 0) ? i0 / norm : 0.f;
    wgt[(size_t)pt * NS_ + 1] = (cnt > 1) ? i1 / norm : 0.f;
    wgt[(size_t)pt * NS_ + 2] = (cnt > 2) ? i2 / norm : 0.f;
}

// ---------------------------------------------------------------------------
// K1: gather+interp -> bf16 LDS tile; MFMA matmul0 with fragment-major w0F
// (coalesced B loads); y0 stored bf16-packed in MFMA fragment layout
// (uint2 per lane per nt, coalesced); BN0 stats on the ROUNDED values.
// ---------------------------------------------------------------------------
__global__ __launch_bounds__(256) void fused1_kernel(
    const float* __restrict__ feat1, const float* __restrict__ feat2,
    const int* __restrict__ sel, const float* __restrict__ wgt,
    const unsigned short* __restrict__ w0F, const float* __restrict__ b0,
    uint2* __restrict__ y0w, float* __restrict__ slots0)
{
    __shared__ unsigned short xstage[64][CIN_ + 8];   // pitch 200 shorts
    __shared__ int   selL[64][NS_];
    __shared__ float wgtL[64][NS_];
    __shared__ float wsum[4][CM_], wsq[4][CM_];

    const int t = threadIdx.x;
    const int blk = blockIdx.x;
    const int pbase = blk * 64;
    const int bidx = blk >> 10;                 // 1024 blocks per batch

    if (t < 64 * NS_) {
        ((int*)selL)[t]   = sel[(size_t)pbase * NS_ + t];
        ((float*)wgtL)[t] = wgt[(size_t)pbase * NS_ + t];
    }
    __syncthreads();

    // feat1 -> xstage[:, 0:64]
    #pragma unroll
    for (int i = 0; i < 4; i++) {
        int idx = t + i * 256;
        int p = idx >> 4, c4 = (idx & 15) << 2;
        float4 f = *(const float4*)(feat1 + (size_t)(pbase + p) * C1_ + c4);
        ushort4 u;
        u.x = f2bf(f.x); u.y = f2bf(f.y); u.z = f2bf(f.z); u.w = f2bf(f.w);
        *(ushort4*)&xstage[p][c4] = u;
    }
    // IDW interp -> xstage[:, 64:192]
    const float* f2b = feat2 + (size_t)bidx * NPT * C2_;
    #pragma unroll
    for (int i = 0; i < 8; i++) {
        int idx = t + i * 256;
        int p = idx >> 5, c4 = (idx & 31) << 2;
        float ax = 0.f, ay = 0.f, az = 0.f, aw = 0.f;
        #pragma unroll
        for (int j = 0; j < NS_; j++) {
            float wj = wgtL[p][j];
            const float4 f = *(const float4*)(f2b + (size_t)selL[p][j] * C2_ + c4);
            ax += wj * f.x; ay += wj * f.y; az += wj * f.z; aw += wj * f.w;
        }
        ushort4 u;
        u.x = f2bf(ax); u.y = f2bf(ay); u.z = f2bf(az); u.w = f2bf(aw);
        *(ushort4*)&xstage[p][C1_ + c4] = u;
    }
    __syncthreads();

    const int wv = t >> 6, lane = t & 63;
    const int m = lane & 15, q = lane >> 4;
    const unsigned short* arow = &xstage[wv * 16 + m][q * 8];

    floatx4 acc[8];
    #pragma unroll
    for (int nt = 0; nt < 8; nt++) acc[nt] = (floatx4){0.f, 0.f, 0.f, 0.f};

    #pragma unroll
    for (int kk = 0; kk < 6; kk++) {
        short8 a = *(const short8*)(arow + kk * 32);
        #pragma unroll
        for (int nt = 0; nt < 8; nt++) {
            short8 bw = *(const short8*)(w0F + ((size_t)(kk * 8 + nt) * 64 + lane) * 8);
            acc[nt] = __builtin_amdgcn_mfma_f32_16x16x32_bf16(a, bw, acc[nt], 0, 0, 0);
        }
    }

    // epilogue: round to bf16, store frag-packed, stats on rounded values
    #pragma unroll
    for (int nt = 0; nt < 8; nt++) {
        int n = nt * 16 + m;
        float bv = b0[n];
        unsigned u0 = packbf(acc[nt][0] + bv, acc[nt][1] + bv);
        unsigned u1 = packbf(acc[nt][2] + bv, acc[nt][3] + bv);
        y0w[((size_t)(blk * 4 + wv) * 8 + nt) * 64 + lane] = make_uint2(u0, u1);
        float v0 = bflo(u0), v1 = bfhi(u0), v2 = bflo(u1), v3 = bfhi(u1);
        float s  = v0 + v1 + v2 + v3;
        float q2 = v0 * v0 + v1 * v1 + v2 * v2 + v3 * v3;
        s += __shfl_xor(s, 16, 64); q2 += __shfl_xor(q2, 16, 64);
        s += __shfl_xor(s, 32, 64); q2 += __shfl_xor(q2, 32, 64);
        if (q == 0) { wsum[wv][n] = s; wsq[wv][n] = q2; }
    }
    __syncthreads();

    float* slot = slots0 + (size_t)(blk & (NSLOT - 1)) * 256;
    if (t < CM_)
        atomicAdd(&slot[t], wsum[0][t] + wsum[1][t] + wsum[2][t] + wsum[3][t]);
    else
        atomicAdd(&slot[t], wsq[0][t - CM_] + wsq[1][t - CM_] + wsq[2][t - CM_] + wsq[3][t - CM_]);
}

// ---------------------------------------------------------------------------
// K2: reduce slots0 -> BN0 scale/shift; load y0 frags (coalesced), BN0+ReLU,
// transform to A-layout via LDS; MFMA matmul1 with w1F; y1 frag-packed bf16
// + BN1 stats (on rounded values).
// ---------------------------------------------------------------------------
__global__ __launch_bounds__(256) void fused2_kernel(
    const uint2* __restrict__ y0w, const float* __restrict__ slots0,
    const float* __restrict__ g0, const float* __restrict__ be0,
    const unsigned short* __restrict__ w1F, const float* __restrict__ b1,
    uint2* __restrict__ y1w, float* __restrict__ slots1)
{
    __shared__ unsigned short x1s[64][CM_ + 8];   // pitch 136 shorts
    __shared__ float scl[CM_], shf[CM_];
    __shared__ float wsum[4][CM_], wsq[4][CM_];

    const int t = threadIdx.x;
    const int blk = blockIdx.x;

    if (t < CM_) {
        float s = 0.f, q2 = 0.f;
        #pragma unroll
        for (int sl = 0; sl < NSLOT; sl++) {
            s  += slots0[sl * 256 + t];
            q2 += slots0[sl * 256 + CM_ + t];
        }
        const float invn = 1.0f / (float)NTOT;
        float mu = s * invn, var = q2 * invn - mu * mu;
        float sc = g0[t] * rsqrtf(var + BN_EPS_);
        scl[t] = sc; shf[t] = be0[t] - mu * sc;
    }
    __syncthreads();

    const int wv = t >> 6, lane = t & 63;
    const int m = lane & 15, q = lane >> 4;
    float sclv[8], shfv[8];
    #pragma unroll
    for (int nt = 0; nt < 8; nt++) {
        sclv[nt] = scl[nt * 16 + m];
        shfv[nt] = shf[nt * 16 + m];
    }

    // y0 frags -> BN0+ReLU -> bf16 A-tile in LDS
    #pragma unroll
    for (int nt = 0; nt < 8; nt++) {
        uint2 u = y0w[((size_t)(blk * 4 + wv) * 8 + nt) * 64 + lane];
        float v0 = fmaxf(bflo(u.x) * sclv[nt] + shfv[nt], 0.f);
        float v1 = fmaxf(bfhi(u.x) * sclv[nt] + shfv[nt], 0.f);
        float v2 = fmaxf(bflo(u.y) * sclv[nt] + shfv[nt], 0.f);
        float v3 = fmaxf(bfhi(u.y) * sclv[nt] + shfv[nt], 0.f);
        int col = nt * 16 + m, rb = wv * 16 + q * 4;
        x1s[rb + 0][col] = f2bf(v0);
        x1s[rb + 1][col] = f2bf(v1);
        x1s[rb + 2][col] = f2bf(v2);
        x1s[rb + 3][col] = f2bf(v3);
    }
    __syncthreads();

    const unsigned short* arow = &x1s[wv * 16 + m][q * 8];
    floatx4 acc[8];
    #pragma unroll
    for (int nt = 0; nt < 8; nt++) acc[nt] = (floatx4){0.f, 0.f, 0.f, 0.f};

    #pragma unroll
    for (int kk = 0; kk < 4; kk++) {
        short8 a = *(const short8*)(arow + kk * 32);
        #pragma unroll
        for (int nt = 0; nt < 8; nt++) {
            short8 bw = *(const short8*)(w1F + ((size_t)(kk * 8 + nt) * 64 + lane) * 8);
            acc[nt] = __builtin_amdgcn_mfma_f32_16x16x32_bf16(a, bw, acc[nt], 0, 0, 0);
        }
    }

    #pragma unroll
    for (int nt = 0; nt < 8; nt++) {
        int n = nt * 16 + m;
        float bv = b1[n];
        unsigned u0 = packbf(acc[nt][0] + bv, acc[nt][1] + bv);
        unsigned u1 = packbf(acc[nt][2] + bv, acc[nt][3] + bv);
        y1w[((size_t)(blk * 4 + wv) * 8 + nt) * 64 + lane] = make_uint2(u0, u1);
        float v0 = bflo(u0), v1 = bfhi(u0), v2 = bflo(u1), v3 = bfhi(u1);
        float s  = v0 + v1 + v2 + v3;
        float q2 = v0 * v0 + v1 * v1 + v2 * v2 + v3 * v3;
        s += __shfl_xor(s, 16, 64); q2 += __shfl_xor(q2, 16, 64);
        s += __shfl_xor(s, 32, 64); q2 += __shfl_xor(q2, 32, 64);
        if (q == 0) { wsum[wv][n] = s; wsq[wv][n] = q2; }
    }
    __syncthreads();

    float* slot = slots1 + (size_t)(blk & (NSLOT - 1)) * 256;
    if (t < CM_)
        atomicAdd(&slot[t], wsum[0][t] + wsum[1][t] + wsum[2][t] + wsum[3][t]);
    else
        atomicAdd(&slot[t], wsq[0][t - CM_] + wsq[1][t - CM_] + wsq[2][t - CM_] + wsq[3][t - CM_]);
}

// ---------------------------------------------------------------------------
// K3: reduce slots1 -> BN1+ReLU on y1 frags -> f32 row-major out.
// ---------------------------------------------------------------------------
__global__ __launch_bounds__(256) void bn_out_kernel(
    const uint2* __restrict__ y1w, const float* __restrict__ slots1,
    const float* __restrict__ g1, const float* __restrict__ be1,
    float* __restrict__ out)
{
    __shared__ float scl[CM_], shf[CM_];
    const int t = threadIdx.x;
    const int blk = blockIdx.x;

    if (t < CM_) {
        float s = 0.f, q2 = 0.f;
        #pragma unroll
        for (int sl = 0; sl < NSLOT; sl++) {
            s  += slots1[sl * 256 + t];
            q2 += slots1[sl * 256 + CM_ + t];
        }
        const float invn = 1.0f / (float)NTOT;
        float mu = s * invn, var = q2 * invn - mu * mu;
        float sc = g1[t] * rsqrtf(var + BN_EPS_);
        scl[t] = sc; shf[t] = be1[t] - mu * sc;
    }
    __syncthreads();

    const int wv = t >> 6, lane = t & 63;
    const int m = lane & 15, q = lane >> 4;

    #pragma unroll
    for (int nt = 0; nt < 8; nt++) {
        uint2 u = y1w[((size_t)(blk * 4 + wv) * 8 + nt) * 64 + lane];
        int n = nt * 16 + m;
        float sc = scl[n], sh = shf[n];
        int rb = blk * 64 + wv * 16 + q * 4;
        out[(size_t)(rb + 0) * CM_ + n] = fmaxf(bflo(u.x) * sc + sh, 0.f);
        out[(size_t)(rb + 1) * CM_ + n] = fmaxf(bfhi(u.x) * sc + sh, 0.f);
        out[(size_t)(rb + 2) * CM_ + n] = fmaxf(bflo(u.y) * sc + sh, 0.f);
        out[(size_t)(rb + 3) * CM_ + n] = fmaxf(bfhi(u.y) * sc + sh, 0.f);
    }
}

// ---------------------------------------------------------------------------
extern "C" void kernel_launch(void* const* d_in, const int* in_sizes, int n_in,
                              void* d_out, int out_size, void* d_ws, size_t ws_size,
                              hipStream_t stream)
{
    const float* xyz1  = (const float*)d_in[0];
    const float* xyz2  = (const float*)d_in[1];
    const float* feat1 = (const float*)d_in[2];
    const float* feat2 = (const float*)d_in[3];
    const float* w0    = (const float*)d_in[4];
    const float* b0    = (const float*)d_in[5];
    const float* g0    = (const float*)d_in[6];
    const float* be0   = (const float*)d_in[7];
    const float* w1    = (const float*)d_in[8];
    const float* b1    = (const float*)d_in[9];
    const float* g1    = (const float*)d_in[10];
    const float* be1   = (const float*)d_in[11];
    float* out = (float*)d_out;

    char* ws = (char*)d_ws;
    // ws: slots0 32K | slots1 32K | sel 1.5M | wgt 1.5M | w0F 48K | w1F 32K
    //     | y0w 33.5M | y1w 33.5M
    float* slots0       = (float*)(ws);
    float* slots1       = (float*)(ws + (size_t)NSLOT * 256 * 4);
    char*  p            = ws + 2 * (size_t)NSLOT * 256 * 4;
    int*   sel          = (int*)p;             p += (size_t)NTOT * NS_ * 4;
    float* wgt          = (float*)p;           p += (size_t)NTOT * NS_ * 4;
    unsigned short* w0F = (unsigned short*)p;  p += (size_t)CIN_ * CM_ * 2;
    unsigned short* w1F = (unsigned short*)p;  p += (size_t)CM_ * CM_ * 2;
    uint2* y0w          = (uint2*)p;           p += (size_t)NTOT * CM_ * 2;
    uint2* y1w          = (uint2*)p;

    hipMemsetAsync(ws, 0, 2 * (size_t)NSLOT * 256 * 4, stream);  // zero stat slots

    prep_knn_kernel<<<20 + NTOT / 256, 256, 0, stream>>>(w0, w1, xyz1, xyz2,
                                                         w0F, w1F, sel, wgt);
    fused1_kernel<<<NTOT / 64, 256, 0, stream>>>(feat1, feat2, sel, wgt,
                                                 w0F, b0, y0w, slots0);
    fused2_kernel<<<NTOT / 64, 256, 0, stream>>>(y0w, slots0, g0, be0,
                                                 w1F, b1, y1w, slots1);
    bn_out_kernel<<<NTOT / 64, 256, 0, stream>>>(y1w, slots1, g1, be1, out);
}